// Round 10
// baseline (773.621 us; speedup 1.0000x reference)
//
#include <hip/hip_runtime.h>
#include <hip/hip_cooperative_groups.h>
#include <hip/hip_bf16.h>
#include <math.h>

namespace cg = cooperative_groups;

typedef __bf16 bf16_t;
typedef __attribute__((ext_vector_type(8))) __bf16 bf16x8;
typedef __attribute__((ext_vector_type(4))) float f32x4;
typedef __attribute__((ext_vector_type(16))) float f32x16;

#define S_LEN 2048
#define DM    2048
#define NH    16
#define HD    128
#define MTOT  4096   // B*S

__device__ inline float finz(float v) {
    return (v == v && fabsf(v) < 1e30f) ? v : 0.f;
}

__device__ inline void gload_lds16(const bf16_t* g, bf16_t* l) {
    __builtin_amdgcn_global_load_lds(
        (const __attribute__((address_space(1))) void*)g,
        (__attribute__((address_space(3))) void*)l, 16, 0, 0);
}

// C/D row index within a 32x32 mfma tile: row = (g&3) + 8*(g>>2) + 4*hi
__device__ __forceinline__ int crow4(int g, int hi) {
    return (g & 3) + ((g >> 2) << 3) + (hi << 2);
}
__device__ __forceinline__ unsigned pk2(float x, float y) {
    union { bf16_t h; unsigned short u; } a, b;
    a.h = (bf16_t)x; b.h = (bf16_t)y;
    return (unsigned)a.u | ((unsigned)b.u << 16);
}
__device__ __forceinline__ bf16x8 pack4(unsigned w0, unsigned w1, unsigned w2, unsigned w3) {
    union { unsigned w[4]; bf16x8 v; } u;
    u.w[0] = w0; u.w[1] = w1; u.w[2] = w2; u.w[3] = w3;
    return u.v;
}

#define MFMA16(a, b, c) __builtin_amdgcn_mfma_f32_16x16x32_bf16(a, b, c, 0, 0, 0)
#define MFMA32(a, b, c) __builtin_amdgcn_mfma_f32_32x32x16_bf16(a, b, c, 0, 0, 0)

// ---------------------------------------------------------------------------
// GEMM tile body (proven m97 structure, R2/R7/R8: ~640 TF, 0 conflicts).
// Called by a 4-wave instance (t = 0..255, Shm = 32KB private LDS region).
// __syncthreads() is BLOCK-wide: both instances execute identical barrier
// sequences (same K-loop count; epilogue barriers unconditional).
// mode 2: bf16 (m,e) | 3: fp32 (m,e) | 4: fused QKV (nb>=32 -> V^T in-LDS
// transpose + coalesced store; nb<32 -> Q/K RoPE via rtab).
// ---------------------------------------------------------------------------
__device__ __forceinline__ void gemm_tile(
    bf16_t* __restrict__ Shm, const bf16_t* __restrict__ A,
    const bf16_t* __restrict__ W, void* __restrict__ Cv,
    const float2* __restrict__ rtab, int mb, int nb, int mode, int t)
{
    bf16_t* As = Shm;
    bf16_t* Ws = Shm + 128*64;

    const int wv   = t >> 6;
    const int lane = t & 63;
    const int c16  = lane & 15;
    const int quad = lane >> 4;
    const int wm   = wv & 1;
    const int wn   = wv >> 1;
    const int c7   = c16 & 7;

    const int srow = lane >> 3;           // 0..7
    const int sphy = (lane & 7) ^ srow;   // swizzled chunk ((row&7)==srow)
    const bf16_t* Ab = A + (size_t)(mb*128 + wv*32 + srow)*DM + sphy*8;
    const bf16_t* Wb = W + (size_t)(nb*128 + wv*32 + srow)*DM + sphy*8;

    f32x4 acc[4][4];
    #pragma unroll
    for (int i = 0; i < 4; ++i)
        #pragma unroll
        for (int j = 0; j < 4; ++j)
            acc[i][j] = (f32x4){0.f, 0.f, 0.f, 0.f};

    for (int kb = 0; kb < DM/64; ++kb) {
        __syncthreads();
        #pragma unroll
        for (int i = 0; i < 4; ++i) {
            gload_lds16(Ab + (size_t)kb*64 + (size_t)i*8*DM, As + (wv*32 + i*8)*64);
            gload_lds16(Wb + (size_t)kb*64 + (size_t)i*8*DM, Ws + (wv*32 + i*8)*64);
        }
        __syncthreads();

        #pragma unroll
        for (int kk = 0; kk < 2; ++kk) {
            const int ph = ((kk*4 + quad) ^ c7) * 8;
            bf16x8 af[4], bfr[4];
            #pragma unroll
            for (int mt = 0; mt < 4; ++mt)
                af[mt] = *(const bf16x8*)(As + (wm*64 + mt*16 + c16)*64 + ph);
            #pragma unroll
            for (int nt = 0; nt < 4; ++nt)
                bfr[nt] = *(const bf16x8*)(Ws + (nt*32 + wn*16 + c16)*64 + ph);
            #pragma unroll
            for (int mt = 0; mt < 4; ++mt)
                #pragma unroll
                for (int nt = 0; nt < 4; ++nt)
                    acc[mt][nt] = MFMA16(af[mt], bfr[nt], acc[mt][nt]);
        }
    }

    // epilogue with UNCONDITIONAL barriers (dual-instance alignment).
    const bool vpath = (mode == 4 && nb >= 32);
    __syncthreads();   // all waves of BOTH instances done reading LDS
    if (vpath) {
        #pragma unroll
        for (int mt = 0; mt < 4; ++mt) {
            #pragma unroll
            for (int r = 0; r < 4; ++r) {
                const int sl = wm*64 + mt*16 + quad*4 + r;   // s within tile
                #pragma unroll
                for (int nt = 0; nt < 4; ++nt) {
                    const int dl = nt*32 + wn*16 + c16;      // d within tile
                    Shm[dl*128 + (sl ^ ((dl & 15) << 3))] =
                        (bf16_t)finz(acc[mt][nt][r]);
                }
            }
        }
    }
    __syncthreads();
    if (vpath) {
        const int hh  = nb & 15;
        const int b   = (mb*128) >> 11;
        const int s0t = (mb*128) & (S_LEN - 1);
        bf16_t* VT = (bf16_t*)Cv + (size_t)2 * MTOT * DM;
        #pragma unroll
        for (int p = 0; p < 8; ++p) {
            int idx = p*256 + t;
            int dl  = idx >> 4;           // 0..127
            int s0  = (idx & 15) * 8;     // 0..120
            bf16x8 v = *(const bf16x8*)&Shm[dl*128 + (s0 ^ ((dl & 15) << 3))];
            *(bf16x8*)(VT + ((size_t)(b*NH + hh)*HD + dl)*S_LEN + s0t + s0) = v;
        }
        return;
    }

    #pragma unroll
    for (int mt = 0; mt < 4; ++mt) {
        #pragma unroll
        for (int r = 0; r < 4; ++r) {
            const int m = mb*128 + wm*64 + mt*16 + quad*4 + r;
            if (mode == 2) {
                bf16_t* C = (bf16_t*)Cv;
                size_t base = (size_t)m*DM + nb*128;
                #pragma unroll
                for (int nt = 0; nt < 4; ++nt)
                    C[base + nt*32 + wn*16 + c16] = (bf16_t)finz(acc[mt][nt][r]);
            } else if (mode == 3) {
                float* C = (float*)Cv;
                size_t base = (size_t)m*DM + nb*128;
                #pragma unroll
                for (int nt = 0; nt < 4; ++nt)
                    C[base + nt*32 + wn*16 + c16] = finz(acc[mt][nt][r]);
            } else {  // mode 4, g < 2: Q or K with RoPE
                const int g  = nb >> 4;
                const int hh = nb & 15;
                bf16_t* C = (bf16_t*)Cv + (size_t)g * MTOT * DM;
                const int b = m >> 11;
                const int s = m & (S_LEN - 1);
                size_t base = ((size_t)(b*NH + hh)*S_LEN + s)*HD;
                #pragma unroll
                for (int nt = 0; nt < 2; ++nt) {
                    int t64 = nt*32 + wn*16 + c16;        // 0..63
                    float2 cs2 = rtab[s*64 + t64];
                    float lo  = acc[mt][nt  ][r];
                    float hi2 = acc[mt][nt+2][r];
                    C[base + t64     ] = (bf16_t)finz(lo*cs2.x - hi2*cs2.y);
                    C[base + t64 + 64] = (bf16_t)finz(hi2*cs2.x + lo*cs2.y);
                }
            }
        }
    }
}

// ---------------------------------------------------------------------------
// Fully-fused MHA: ONE cooperative kernel, grid 256 x 512 (1 block/CU,
// 8 waves/CU), grid.sync() between phases. Removes all inter-kernel launch
// gaps (~110us measured residual in R9).
//  A: converts (x, 4 weights) + RoPE table, grid-stride. Per-block dtype
//     probe fallback (mode==2).
//  B: QKV GEMM: 1536 tiles, 6/block, dual 4-wave instances (32KB LDS each).
//  C: flash attention (R9 body verbatim; bh=bid&31 -> XCD-local K/V).
//  D: out-projection: 512 tiles, 2/block, dual-instance.
// ---------------------------------------------------------------------------
__global__ __launch_bounds__(512, 1)
void mha_fused(const void* __restrict__ x_raw,
               const void* __restrict__ w0, const void* __restrict__ w1,
               const void* __restrict__ w2, const void* __restrict__ w3,
               bf16_t* __restrict__ xb, bf16_t* __restrict__ wb,
               bf16_t* __restrict__ Qb, bf16_t* __restrict__ Ob,
               void* __restrict__ Cout, float2* __restrict__ rtab,
               int mode, int outf)
{
    __shared__ __align__(16) unsigned char ShRaw[98816];   // 96.5 KB union
    cg::grid_group grid = cg::this_grid();

    const int bid = blockIdx.x;   // 0..255
    const int t   = threadIdx.x;  // 0..511
    const int NXE = MTOT*DM;
    const int NWE = DM*DM;

    // ================= Phase A: converts + rope =================
    {
        bool f32in;
        if (mode == 2) {
            int* tot = (int*)ShRaw;
            if (t == 0) *tot = 0;
            __syncthreads();
            int weird = 0;
            const unsigned short* p = (const unsigned short*)x_raw;
            for (int i = t; i < 4096; i += 512) {
                unsigned short u = p[2*i];
                int e = (u >> 7) & 0xFF;
                if (e >= 0xC8 || (e != 0 && e <= 0x38)) weird++;
            }
            atomicAdd(tot, weird);
            __syncthreads();
            f32in = (*tot > 512);
            __syncthreads();
        } else {
            f32in = (mode == 1);
        }

        const int gtid = bid*512 + t;      // 0..131071
        const int GSTR = 256*512;
        if (f32in) {
            for (int i = gtid; i < NXE/4; i += GSTR) {
                float4 v = ((const float4*)x_raw)[i];
                union { bf16_t h[4]; uint2 u; } o;
                o.h[0] = (bf16_t)v.x; o.h[1] = (bf16_t)v.y;
                o.h[2] = (bf16_t)v.z; o.h[3] = (bf16_t)v.w;
                ((uint2*)xb)[i] = o.u;
            }
            const void* wsrc[4] = {w0, w1, w2, w3};
            #pragma unroll
            for (int w = 0; w < 4; ++w) {
                const float4* ws = (const float4*)wsrc[w];
                uint2* wd = (uint2*)(wb + (size_t)w*NWE);
                for (int i = gtid; i < NWE/4; i += GSTR) {
                    float4 v = ws[i];
                    union { bf16_t h[4]; uint2 u; } o;
                    o.h[0] = (bf16_t)v.x; o.h[1] = (bf16_t)v.y;
                    o.h[2] = (bf16_t)v.z; o.h[3] = (bf16_t)v.w;
                    wd[i] = o.u;
                }
            }
        } else {
            for (int i = gtid; i < NXE/4; i += GSTR)
                ((uint2*)xb)[i] = ((const uint2*)x_raw)[i];
            const void* wsrc[4] = {w0, w1, w2, w3};
            #pragma unroll
            for (int w = 0; w < 4; ++w) {
                const uint2* ws = (const uint2*)wsrc[w];
                uint2* wd = (uint2*)(wb + (size_t)w*NWE);
                for (int i = gtid; i < NWE/4; i += GSTR)
                    wd[i] = ws[i];
            }
        }
        // rope table: exactly one element per thread (131072 total)
        {
            int i = gtid;
            int s = i >> 6, t64 = i & 63;
            float invf = exp2f(-(float)t64 * 0.20762050593046014f);
            float ang  = (float)s * invf;
            float sn, cs;
            sincosf(ang, &sn, &cs);
            rtab[i] = make_float2(cs, sn);
        }
    }
    __threadfence();
    grid.sync();

    // ================= Phase B: QKV projection =================
    {
        const int inst = t >> 8;         // 0/1
        const int t4   = t & 255;
        bf16_t* Shm = (bf16_t*)(ShRaw + inst*32768);
        #pragma unroll
        for (int j2 = 0; j2 < 3; ++j2) {
            int tile = bid + 256*(j2*2 + inst);   // [0,1536)
            gemm_tile(Shm, xb, wb, (void*)Qb, rtab, tile & 31, tile >> 5, 4, t4);
        }
    }
    __threadfence();
    grid.sync();

    // ================= Phase C: flash attention =================
    {
        bf16_t* Ks   = (bf16_t*)ShRaw;             // 16KB, swizzled
        bf16_t* Vs   = (bf16_t*)(ShRaw + 16384);   // 16KB, swizzled
        float*  Ocmb = (float*)(ShRaw + 32768);    // [4][4096] = 64KB
        float*  lcmb = (float*)(ShRaw + 98304);    // [4][32]
        const bf16_t* Q  = Qb;
        const bf16_t* K  = Qb + (size_t)NXE;
        const bf16_t* VT = Qb + (size_t)2*NXE;
        bf16_t* O = Ob;

        const int wid  = t >> 6;
        const int lane = t & 63;
        const int qw   = wid & 3;
        const int kh   = wid >> 2;
        const int c32  = lane & 31;
        const int hi   = lane >> 5;
        const int bh   = bid & 31;    // XCD = bid%8 = bh%8 -> K/V L2-local
        const int ix   = bid >> 5;    // 0..7

        const float scale = 0.08838834764831845f;  // 1/sqrt(128)
        const float SMAX  = 12.0f;

        bf16x8 onesf;
        #pragma unroll
        for (int j = 0; j < 8; ++j) onesf[j] = (bf16_t)1.0f;

        for (int pass = 0; pass < 2; ++pass) {
            const int Qt   = pass ? (15 - ix) : ix;
            const int qt0  = Qt * 128;
            const int qrow = qt0 + qw*32 + c32;
            const int qmin = qt0 + qw*32;

            bf16x8 qf[8];
            {
                const bf16_t* qp = Q + ((size_t)bh*S_LEN + qrow)*HD;
                #pragma unroll
                for (int s = 0; s < 8; ++s)
                    qf[s] = *(const bf16x8*)(qp + s*16 + hi*8);
            }

            f32x16 oacc[4];
            f32x16 lacc;
            #pragma unroll
            for (int e = 0; e < 16; ++e) lacc[e] = 0.f;
            #pragma unroll
            for (int dt = 0; dt < 4; ++dt)
                #pragma unroll
                for (int e = 0; e < 16; ++e) oacc[dt][e] = 0.f;

            const int ktend = 2*Qt + 1;
            for (int kt = 0; kt <= ktend; ++kt) {
                __syncthreads();
                #pragma unroll
                for (int j = 0; j < 2; ++j) {
                    int base = wid*8 + j*4;
                    int rg   = base + (lane >> 4);
                    int ph   = (lane & 15) ^ (rg & 7);
                    gload_lds16(K + ((size_t)bh*S_LEN + kt*64 + rg)*HD + ph*8,
                                Ks + base*128);
                }
                #pragma unroll
                for (int j = 0; j < 2; ++j) {
                    int base = wid*16 + j*8;
                    int rg   = base + (lane >> 3);
                    int ph   = (lane & 7) ^ (rg & 7);
                    gload_lds16(VT + ((size_t)bh*HD + rg)*S_LEN + kt*64 + ph*8,
                                Vs + base*64);
                }
                __syncthreads();

                const int kbase = kt*64 + kh*32;
                if (kbase > qmin + 31) continue;

                f32x16 sacc;
                #pragma unroll
                for (int e = 0; e < 16; ++e) sacc[e] = 0.f;
                const int krow = kh*32 + c32;
                const int ksw  = krow & 7;
                __builtin_amdgcn_s_setprio(1);
                #pragma unroll
                for (int s = 0; s < 8; ++s) {
                    bf16x8 kf = *(const bf16x8*)(Ks + krow*128 + (((s*2 + hi) ^ ksw) << 3));
                    sacc = MFMA32(kf, qf[s], sacc);
                }
                __builtin_amdgcn_s_setprio(0);

                float p[16];
                if (kbase + 31 > qmin) {
                    #pragma unroll
                    for (int g = 0; g < 16; ++g) {
                        int kg = kbase + crow4(g, hi);
                        p[g] = (kg <= qrow) ? __expf(sacc[g]*scale - SMAX) : 0.f;
                    }
                } else {
                    #pragma unroll
                    for (int g = 0; g < 16; ++g)
                        p[g] = __expf(sacc[g]*scale - SMAX);
                }

                unsigned a0 = pk2(p[0],  p[1]),  b0 = pk2(p[2],  p[3]);
                unsigned a1 = pk2(p[4],  p[5]),  b1 = pk2(p[6],  p[7]);
                unsigned a2 = pk2(p[8],  p[9]),  b2 = pk2(p[10], p[11]);
                unsigned a3 = pk2(p[12], p[13]), b3 = pk2(p[14], p[15]);
                asm volatile("v_permlane32_swap_b32 %0, %1" : "+v"(a0), "+v"(a1));
                asm volatile("v_permlane32_swap_b32 %0, %1" : "+v"(b0), "+v"(b1));
                asm volatile("v_permlane32_swap_b32 %0, %1" : "+v"(a2), "+v"(a3));
                asm volatile("v_permlane32_swap_b32 %0, %1" : "+v"(b2), "+v"(b3));
                bf16x8 pa0 = pack4(a0, b0, a1, b1);
                bf16x8 pa1 = pack4(a2, b2, a3, b3);

                const int ks0 = kh*2 + 0, ks1 = kh*2 + 1;
                __builtin_amdgcn_s_setprio(1);
                lacc = MFMA32(pa0, onesf, lacc);
                lacc = MFMA32(pa1, onesf, lacc);
                #pragma unroll
                for (int dt = 0; dt < 4; ++dt) {
                    const int vrow = dt*32 + c32;
                    const int vsw  = vrow & 7;
                    bf16x8 vf0 = *(const bf16x8*)(Vs + vrow*64 + (((ks0*2 + hi) ^ vsw) << 3));
                    oacc[dt] = MFMA32(pa0, vf0, oacc[dt]);
                    bf16x8 vf1 = *(const bf16x8*)(Vs + vrow*64 + (((ks1*2 + hi) ^ vsw) << 3));
                    oacc[dt] = MFMA32(pa1, vf1, oacc[dt]);
                }
                __builtin_amdgcn_s_setprio(0);
            } // kt

            if (kh == 1) {
                #pragma unroll
                for (int g = 0; g < 16; ++g) {
                    int ql = crow4(g, hi);
                    #pragma unroll
                    for (int dt = 0; dt < 4; ++dt)
                        Ocmb[qw*4096 + ql*128 + dt*32 + c32] = oacc[dt][g];
                }
                if (c32 == 0) {
                    #pragma unroll
                    for (int g = 0; g < 16; ++g)
                        lcmb[qw*32 + crow4(g, hi)] = lacc[g];
                }
            }
            __syncthreads();
            if (kh == 0) {
                const int b = bh >> 4, h = bh & 15;
                #pragma unroll
                for (int g = 0; g < 16; ++g) {
                    int ql = crow4(g, hi);
                    int qg = qt0 + qw*32 + ql;
                    float lt = lacc[g] + lcmb[qw*32 + ql];
                    float rl = 1.0f / fmaxf(lt, 1e-37f);
                    #pragma unroll
                    for (int dt = 0; dt < 4; ++dt) {
                        float v = oacc[dt][g] + Ocmb[qw*4096 + ql*128 + dt*32 + c32];
                        O[((size_t)(b*S_LEN + qg))*DM + h*HD + dt*32 + c32] =
                            (bf16_t)finz(v*rl);
                    }
                }
            }
            __syncthreads();   // Ocmb/lcmb safe to overwrite next pass
        } // pass
    }
    __threadfence();
    grid.sync();

    // ================= Phase D: output projection =================
    {
        const int inst = t >> 8;
        const int t4   = t & 255;
        bf16_t* Shm = (bf16_t*)(ShRaw + inst*32768);
        bf16_t* Wob = wb + (size_t)3*NWE;
        int tile = bid + 256*inst;                 // [0,512)
        gemm_tile(Shm, Ob, Wob, Cout, rtab, tile & 31, tile >> 5,
                  outf ? 3 : 2, t4);
    }
}

// ---------------------------------------------------------------------------
extern "C" void kernel_launch(void* const* d_in, const int* in_sizes, int n_in,
                              void* d_out, int out_size, void* d_ws, size_t ws_size,
                              hipStream_t stream)
{
    const void* x_raw  = d_in[0];
    const void* Wq_raw = d_in[1];
    const void* Wk_raw = d_in[2];
    const void* Wv_raw = d_in[3];
    const void* Wo_raw = d_in[4];

    const int NX = MTOT*DM;
    const int NW = DM*DM;

    bf16_t* xb  = (bf16_t*)((char*)d_ws + 16);
    bf16_t* Wqb = xb  + NX;   // Wq|Wk|Wv|Wo contiguous
    bf16_t* Qb  = Wqb + 4*(size_t)NW;   // Q|K|VT contiguous
    bf16_t* Ob  = Qb + 3*(size_t)NX;
    float2* rtab = (float2*)(Ob + NX);  // 1 MB RoPE table

    bool out_is_f32 = true;
    {
        void* base = nullptr; size_t sz = 0;
        if (hipMemGetAddressRange((hipDeviceptr_t*)&base, &sz,
                                  (hipDeviceptr_t)d_out) == hipSuccess && sz != 0) {
            if (sz < (size_t)out_size * 3) out_is_f32 = false;
        }
    }

    // input dtype from in_sizes (byte sizes); per-block device probe fallback
    int mode = 2;
    if (in_sizes && n_in >= 1) {
        if (in_sizes[0] == NX*4)      mode = 1;   // fp32
        else if (in_sizes[0] == NX*2) mode = 0;   // bf16
    }
    int outf = out_is_f32 ? 1 : 0;

    void* args[] = {
        (void*)&x_raw, (void*)&Wq_raw, (void*)&Wk_raw, (void*)&Wv_raw,
        (void*)&Wo_raw, (void*)&xb, (void*)&Wqb, (void*)&Qb, (void*)&Ob,
        (void*)&d_out, (void*)&rtab, (void*)&mode, (void*)&outf
    };
    hipLaunchCooperativeKernel((const void*)mha_fused, dim3(256), dim3(512),
                               args, 0, stream);
}